// Round 22
// baseline (228.755 us; speedup 1.0000x reference)
//
#include <hip/hip_runtime.h>

#define GH 135
#define GW 240
#define HH 1080
#define WW 1920
#define HWPX (HH*WW)
#define NP 12
#define IT 2               // anchor block-rows per WG (i-strip)
#define JT 12              // anchor blocks (j) per WG
#define NBG 6              // anchor pairs per it-row
#define NIG 68             // ceil(GH/IT)
#define NJG 20             // GW/JT
#define TROWS (IT+8)       // 10 staged target block-rows
#define TBLK (JT+8)        // 20 staged target blocks per dy-row
#define DSTR (TBLK*64+8)   // 1288 dw: 2-quad row rotation (r12 conflict fix)
#define UNITS_ROW (TBLK*16)// 320 16B-units per dy-row (= exactly 5 waves)
#define UNITS_TOT (TROWS*UNITS_ROW) // 3200
#define NTHR 256
#define NACT 216           // 9 dy * (2 it * 6 bg * 2 yh)
#define TT_DW (TROWS*DSTR) // 12880 dw = 51520 B -> 3 WG/CU at VGPR<=85
#define NWG (NIG*NJG)      // 1360 = 8*170 (XCD-exact)
#define NBLK (GH*GW)       // 32400 target blocks
#define ST2_FINAL_OFF 262144   // double-index into d_out for stsum

// Round-22: Pareto combination of measured-best components.
//  - cost kernel = r20 verbatim (A=2 windows, dot chain, VGPR 80 -> 3 waves/
//    SIMD, 190us). r21 proved A=3 @ 2 waves (195us) loses to A=2 @ 3 waves:
//    third controlled test of the traffic<->occupancy trade, same verdict.
//  - st2 = r21 verbatim (16 blocks x 16 (y,qh) slices/WG, 2025 WGs, ~17us).
//  - gather unchanged (~10us, L3-hot).
// Algebra (r19/r20, absmax 0): ||A-T||^2 -> argmin( stsum_f64 - 2*A.T );
// ||A||^2 common-mode dropped. Staging: async global_load_lds, linear dest
// (5 whole waves/row), inverse-swizzled + clamped src (r11). Swizzle
// (bijective, r5/r12): stored(blk,y,xh)=blk*64+((y*8+xh)^4*kb^16*(y>>2)),
// kb=(blk>>1)&7. DSTR%32=8 -> 2-quad row rotation (r12).

// 8-px fp32 DOT chain + f64 accumulate (argmin-exact, proven r19-r21)
#define CHAINAT(AV0, AV1, T0, T1, ACC) do { \
    float _s = (AV0).x * (T0).x; \
    _s = fmaf((AV0).y, (T0).y, _s); \
    _s = fmaf((AV0).z, (T0).z, _s); \
    _s = fmaf((AV0).w, (T0).w, _s); \
    _s = fmaf((AV1).x, (T1).x, _s); \
    _s = fmaf((AV1).y, (T1).y, _s); \
    _s = fmaf((AV1).z, (T1).z, _s); \
    _s = fmaf((AV1).w, (T1).w, _s); \
    (ACC) += (double)_s; } while(0)

__device__ __forceinline__ void async_copy16(const float* gp, float* lp) {
#if __has_builtin(__builtin_amdgcn_global_load_lds)
    __builtin_amdgcn_global_load_lds(
        (const __attribute__((address_space(1))) void*)gp,
        (__attribute__((address_space(3))) void*)lp, 16, 0, 0);
#else
    *(float4*)lp = *(const float4*)gp;
#endif
}

// ---- ||T||^2 per target block: 16 blocks x 16 (y,qh) slices per WG (r21) ----
__global__ void __launch_bounds__(256) hbma_st2_kernel(const float* __restrict__ T,
                                                       double* __restrict__ stsum) {
    __shared__ double red[256];
    const int tid = threadIdx.x;
    const int b16 = tid & 15;          // block within WG (fast -> coalesced)
    const int s   = tid >> 4;          // slice: y = s&7, qh = s>>3
    const int bb  = blockIdx.x * 16 + b16;
    const int gi = bb / GW, gj = bb % GW;
    const int y  = s & 7, qh = s >> 3;
    const float* base = T + (size_t)(gi * 8 + y) * WW + gj * 8 + (size_t)(qh * 6) * HWPX;
    double acc = 0.0;
#pragma unroll
    for (int q = 0; q < 6; ++q) {
        const float* r = base + (size_t)q * HWPX;
        const float4 v0 = *(const float4*)(r);
        const float4 v1 = *(const float4*)(r + 4);
        acc += (double)v0.x * v0.x + (double)v0.y * v0.y
             + (double)v0.z * v0.z + (double)v0.w * v0.w
             + (double)v1.x * v1.x + (double)v1.y * v1.y
             + (double)v1.z * v1.z + (double)v1.w * v1.w;
    }
    red[s * 16 + b16] = acc;
    __syncthreads();
    if (tid < 16) {                    // one summer per target block
        double t = 0.0;
#pragma unroll
        for (int k = 0; k < 16; ++k) t += red[k * 16 + tid];
        stsum[blockIdx.x * 16 + tid] = t;
    }
}

__global__ void __launch_bounds__(NTHR, 3)
hbma_cost_kernel(const float* __restrict__ A, const float* __restrict__ T,
                 const double* __restrict__ stsumF, int* __restrict__ bestidx) {
    extern __shared__ float lds[];
    float* Tt = lds;

    // XCD swizzle: 1360 WGs = 8 XCDs x 170
    const int lin = blockIdx.x;
    const int g   = (lin & 7) * (NWG / 8) + (lin >> 3);
    const int ig  = g % NIG, jg = g / NIG;
    const int i0  = ig * IT;
    const int j0  = jg * JT;

    const int tid = threadIdx.x;
    const int dy  = tid / 24;          // 0..8
    const int rem = tid % 24;
    const int it  = rem / 12;          // 0..1
    const int r2  = rem % 12;
    const int bg  = r2 >> 1;           // 0..5 (anchor pair)
    const int yh  = r2 & 1;            // y-half
    const bool act = (tid < NACT);
    const int i   = i0 + it;
    const int gi  = i + dy - 4;
    const bool dyValid = act && (i < GH) && (gi >= 0) && (gi < GH);
    const int dr  = it + dy;           // staged row index 0..9

    int xq[5];                         // per p-pair h: 4*((bg+h)&7) ^ 16*yh
#pragma unroll
    for (int h = 0; h < 5; ++h) xq[h] = (((bg + h) & 7) * 4) ^ (yh << 4);

    double acc0[9], acc1[9];           // SAT accumulators
#pragma unroll
    for (int d = 0; d < 9; ++d) { acc0[d] = 0.0; acc1[d] = 0.0; }

    const int gy0 = (i0 - 4) * 8;
    const int gx0 = (j0 - 4) * 8;
    const size_t arow0 = (size_t)(i * 8 + yh * 4) * WW;
    const int ja = (j0 + 2 * bg) * 8;

    for (int q = 0; q < NP; ++q) {
        const float* Tq = T + (size_t)q * HWPX;
        const float* Aq = A + (size_t)q * HWPX;
        __syncthreads();               // prev compute done before LDS overwrite
        // ---- stage target halo: async DMA, linear dest units, clamped src ----
        for (int w = tid; w < UNITS_TOT; w += NTHR) {
            const int dyr = w / UNITS_ROW;
            const int u   = w - dyr * UNITS_ROW;
            const int blk = u >> 4, v = u & 15;
            const int kb  = (blk >> 1) & 7;
            const int yh2 = v >> 3;
            const int m3  = (v & 7) ^ kb ^ (yh2 << 2);
            const int y   = (yh2 << 2) + (m3 >> 1);
            const int xh4 = m3 & 1;
            int gy = gy0 + dyr * 8 + y;
            int gx = gx0 + blk * 8 + xh4 * 4;
            gy = min(max(gy, 0), HH - 1);
            gx = min(max(gx, 0), WW - 4);
            async_copy16(Tq + (size_t)gy * WW + gx, Tt + dyr * DSTR + u * 4);
        }
        __syncthreads();               // auto vmcnt(0): DMA landed
        // ---- SAT: sliding 10-block window serves 2 anchors x 9 dx.
        //      Anchors loaded per-yi (4 live regs, L1-hot) to stay <=85 VGPR ----
        if (dyValid) {
            const float* tb = Tt + dr * DSTR + bg * 128 + yh * 32;
#pragma unroll
            for (int yi = 0; yi < 4; ++yi) {
                const float* arow_ = Aq + arow0 + (size_t)yi * WW + ja;
                const float4 aw0 = *(const float4*)(arow_);
                const float4 aw1 = *(const float4*)(arow_ + 4);
                const float4 aw2 = *(const float4*)(arow_ + 8);
                const float4 aw3 = *(const float4*)(arow_ + 12);
#pragma unroll
                for (int ph = 0; ph < 2; ++ph) {       // p-chunks of 5: 10-deep ds ILP
                    float4 tw0[5], tw1[5];
#pragma unroll
                    for (int pp = 0; pp < 5; ++pp) {
                        const int p  = ph * 5 + pp;
                        const int o0 = (yi * 8) ^ xq[p >> 1];
                        tw0[pp] = *(const float4*)(tb + p * 64 + o0);
                        tw1[pp] = *(const float4*)(tb + p * 64 + (o0 ^ 4));
                    }
#pragma unroll
                    for (int pp = 0; pp < 5; ++pp) {
                        const int p = ph * 5 + pp;
                        if (p < 9) CHAINAT(aw0, aw1, tw0[pp], tw1[pp], acc0[p]);
                        if (p > 0) CHAINAT(aw2, aw3, tw0[pp], tw1[pp], acc1[p - 1]);
                    }
                }
            }
        }
    }
    // ---- y-half merge via LDS (aliases Tt, barrier-protected) ----
    __syncthreads();
    double* yred = (double*)lds;                     // 108 pairs * 18 f64 = 3888 dw
    const int pairId = (it * NBG + bg) * 9 + dy;
    if (act && yh == 1) {
        double* d = yred + pairId * 18;
#pragma unroll
        for (int k = 0; k < 9; ++k) { d[k] = acc0[k]; d[9 + k] = acc1[k]; }
    }
    __syncthreads();
    double* redc = (double*)(lds + 8192);            // 216 f64 = 432 dw
    int*    redk = (int*)(lds + 8192 + 432);         // 216 int
    if (act && yh == 0) {
        const double* d = yred + pairId * 18;
#pragma unroll
        for (int k = 0; k < 9; ++k) { acc0[k] += d[k]; acc1[k] += d[9 + k]; }
        // stage-1 argmin over dx: V = stsum(exact f64) - 2*SAT.
        // Ascending dx, strict < -> first-k ties (matches np argmin).
#pragma unroll
        for (int a2 = 0; a2 < 2; ++a2) {
            double bc = 1e300; int bk = -1;
            const int jb = j0 + 2 * bg + a2;
#pragma unroll
            for (int dxi = 0; dxi < 9; ++dxi) {
                const int gj = jb + dxi - 4;
                if (dyValid && gj >= 0 && gj < GW) {
                    const double sat = a2 ? acc1[dxi] : acc0[dxi];
                    const double c = stsumF[gi * GW + gj] - 2.0 * sat;
                    if (c < bc) { bc = c; bk = dy * 9 + dxi; }
                }
            }
            redc[(it * 9 + dy) * JT + 2 * bg + a2] = bc;
            redk[(it * 9 + dy) * JT + 2 * bg + a2] = bk;
        }
    }
    __syncthreads();
    // ---- stage-2 argmin over dy (ascending, strict <) ----
    if (tid < IT * JT) {
        const int it2 = tid / JT, jt = tid % JT;
        if (i0 + it2 < GH) {
            double c = 1e300; int k = -1;
#pragma unroll
            for (int dyi = 0; dyi < 9; ++dyi) {
                const double v = redc[(it2 * 9 + dyi) * JT + jt];
                if (v < c) { c = v; k = redk[(it2 * 9 + dyi) * JT + jt]; }
            }
            const int dyi = k / 9, dxi = k % 9;
            const int bi = i0 + it2 + dyi - 4;
            const int bj = j0 + jt + dxi - 4;
            bestidx[(i0 + it2) * GW + j0 + jt] = (bi << 8) | bj;
        }
    }
}

__global__ void __launch_bounds__(256) hbma_gather_kernel(const float* __restrict__ A,
                                                          const int* __restrict__ bestidx,
                                                          float* __restrict__ out) {
    const int tid = blockIdx.x * 256 + threadIdx.x;
    const int q   = tid / (HWPX / 4);
    const int rem = tid % (HWPX / 4);
    const int py  = rem / (WW / 4);
    const int c4  = rem % (WW / 4);
    const int i = py >> 3, y = py & 7;
    const int j = c4 >> 1, xh = (c4 & 1) * 4;
    const int idx = bestidx[i * GW + j];
    const int bi = idx >> 8, bj = idx & 255;
    const float4 v = *(const float4*)(A + (size_t)q * HWPX + (size_t)(bi * 8 + y) * WW + bj * 8 + xh);
    *(float4*)(out + (size_t)q * HWPX + (size_t)py * WW + c4 * 4) = v;
}

extern "C" void kernel_launch(void* const* d_in, const int* in_sizes, int n_in,
                              void* d_out, int out_size, void* d_ws, size_t ws_size,
                              hipStream_t stream) {
    const float* A = (const float*)d_in[0];
    const float* T = (const float*)d_in[1];
    float* out = (float*)d_out;
    int* bestidx = (int*)d_ws;

    // ||T||^2 scratch in d_out (gather fully overwrites it afterwards)
    double* st2f = (double*)d_out + ST2_FINAL_OFF;

    hipFuncSetAttribute((const void*)hbma_cost_kernel,
                        hipFuncAttributeMaxDynamicSharedMemorySize, TT_DW * 4);

    hipLaunchKernelGGL(hbma_st2_kernel, dim3(NBLK / 16), dim3(256),
                       0, stream, T, st2f);
    hipLaunchKernelGGL(hbma_cost_kernel, dim3(NWG), dim3(NTHR), TT_DW * 4, stream,
                       A, T, st2f, bestidx);

    const int total4 = (NP * HWPX) / 4;
    hipLaunchKernelGGL(hbma_gather_kernel, dim3(total4 / 256), dim3(256), 0, stream,
                       A, bestidx, out);
}

// Round 23
// 195.137 us; speedup vs baseline: 1.1723x; 1.1723x over previous
//
#include <hip/hip_runtime.h>

#define GH 135
#define GW 240
#define HH 1080
#define WW 1920
#define HWPX (HH*WW)
#define NP 12
#define IT 2               // anchor block-rows per WG (i-strip)
#define JT 12              // anchor blocks (j) per WG
#define NBG 6              // anchor pairs per it-row
#define NIG 68             // ceil(GH/IT)
#define NJG 20             // GW/JT
#define TROWS (IT+8)       // 10 staged target block-rows
#define TBLK (JT+8)        // 20 staged target blocks per dy-row
#define DSTR (TBLK*64+8)   // 1288 dw: 2-quad row rotation (r12 conflict fix)
#define UNITS_ROW (TBLK*16)// 320 16B-units per dy-row (= exactly 5 waves)
#define UNITS_TOT (TROWS*UNITS_ROW) // 3200
#define NTHR 256
#define NACT 216           // 9 dy * (2 it * 6 bg * 2 yh)
#define TT_DW (TROWS*DSTR) // 12880 dw = 51520 B -> 3 WG/CU at VGPR<=85
#define NWG (NIG*NJG)      // 1360 = 8*170 (XCD-exact)
#define NBLK (GH*GW)       // 32400 target blocks
#define ST2_FINAL_OFF 262144   // d_out fallback scratch (double-index)

// Round-23: FUSE the gather into the cost kernel's epilogue.
//  - Each WG's output depends only on its own argmin (bestpack in LDS), so
//    the separate gather kernel (~18us, serialized after the LAST cost WG)
//    is replaced by a per-WG epilogue whose writes overlap round-2 compute
//    (1360 WGs / ~768 resident = 1.8 rounds). Also deletes one launch and
//    the bestidx global round-trip.
//  - RACE FIX this requires: fused output covers ALL of d_out, so the stsum
//    scratch moves d_out -> d_ws (259KB). Host-side branch: if ws_size is
//    too small, fall back to the r22 path verbatim (proven, 228.75us).
//  - NOTE: fused cost kernel WRITE_SIZE ~97MB is EXPECTED (output), not a
//    spill; spill gate = FETCH (~225MB) + VGPR<=85.
// Cost kernel body = r22/r20 verbatim (190us champion): A=2 windows, dot
// chain (r19 algebra: argmin(stsum_f64 - 2*A.T), ||A||^2 dropped), async
// global_load_lds staging (linear dest, 5 whole waves/row, clamped src),
// bijective swizzle stored(blk,y,xh)=blk*64+((y*8+xh)^4*kb^16*(y>>2)),
// kb=(blk>>1)&7, DSTR%32=8 2-quad rotation, (256,3) -> 3 waves/SIMD.

// 8-px fp32 DOT chain + f64 accumulate (argmin-exact, proven r19-r22)
#define CHAINAT(AV0, AV1, T0, T1, ACC) do { \
    float _s = (AV0).x * (T0).x; \
    _s = fmaf((AV0).y, (T0).y, _s); \
    _s = fmaf((AV0).z, (T0).z, _s); \
    _s = fmaf((AV0).w, (T0).w, _s); \
    _s = fmaf((AV1).x, (T1).x, _s); \
    _s = fmaf((AV1).y, (T1).y, _s); \
    _s = fmaf((AV1).z, (T1).z, _s); \
    _s = fmaf((AV1).w, (T1).w, _s); \
    (ACC) += (double)_s; } while(0)

__device__ __forceinline__ void async_copy16(const float* gp, float* lp) {
#if __has_builtin(__builtin_amdgcn_global_load_lds)
    __builtin_amdgcn_global_load_lds(
        (const __attribute__((address_space(1))) void*)gp,
        (__attribute__((address_space(3))) void*)lp, 16, 0, 0);
#else
    *(float4*)lp = *(const float4*)gp;
#endif
}

// ---- ||T||^2 per target block: 16 blocks x 16 (y,qh) slices per WG (r21) ----
__global__ void __launch_bounds__(256) hbma_st2_kernel(const float* __restrict__ T,
                                                       double* __restrict__ stsum) {
    __shared__ double red[256];
    const int tid = threadIdx.x;
    const int b16 = tid & 15;
    const int s   = tid >> 4;
    const int bb  = blockIdx.x * 16 + b16;
    const int gi = bb / GW, gj = bb % GW;
    const int y  = s & 7, qh = s >> 3;
    const float* base = T + (size_t)(gi * 8 + y) * WW + gj * 8 + (size_t)(qh * 6) * HWPX;
    double acc = 0.0;
#pragma unroll
    for (int q = 0; q < 6; ++q) {
        const float* r = base + (size_t)q * HWPX;
        const float4 v0 = *(const float4*)(r);
        const float4 v1 = *(const float4*)(r + 4);
        acc += (double)v0.x * v0.x + (double)v0.y * v0.y
             + (double)v0.z * v0.z + (double)v0.w * v0.w
             + (double)v1.x * v1.x + (double)v1.y * v1.y
             + (double)v1.z * v1.z + (double)v1.w * v1.w;
    }
    red[s * 16 + b16] = acc;
    __syncthreads();
    if (tid < 16) {
        double t = 0.0;
#pragma unroll
        for (int k = 0; k < 16; ++k) t += red[k * 16 + tid];
        stsum[blockIdx.x * 16 + tid] = t;
    }
}

template<bool FUSED>
__global__ void __launch_bounds__(NTHR, 3)
hbma_cost_kernel(const float* __restrict__ A, const float* __restrict__ T,
                 const double* __restrict__ stsumF, int* __restrict__ bestidx,
                 float* __restrict__ out) {
    extern __shared__ float lds[];
    float* Tt = lds;

    // XCD swizzle: 1360 WGs = 8 XCDs x 170
    const int lin = blockIdx.x;
    const int g   = (lin & 7) * (NWG / 8) + (lin >> 3);
    const int ig  = g % NIG, jg = g / NIG;
    const int i0  = ig * IT;
    const int j0  = jg * JT;

    const int tid = threadIdx.x;
    const int dy  = tid / 24;          // 0..8
    const int rem = tid % 24;
    const int it  = rem / 12;          // 0..1
    const int r2  = rem % 12;
    const int bg  = r2 >> 1;           // 0..5 (anchor pair)
    const int yh  = r2 & 1;            // y-half
    const bool act = (tid < NACT);
    const int i   = i0 + it;
    const int gi  = i + dy - 4;
    const bool dyValid = act && (i < GH) && (gi >= 0) && (gi < GH);
    const int dr  = it + dy;           // staged row index 0..9

    int xq[5];                         // per p-pair h: 4*((bg+h)&7) ^ 16*yh
#pragma unroll
    for (int h = 0; h < 5; ++h) xq[h] = (((bg + h) & 7) * 4) ^ (yh << 4);

    double acc0[9], acc1[9];           // SAT accumulators
#pragma unroll
    for (int d = 0; d < 9; ++d) { acc0[d] = 0.0; acc1[d] = 0.0; }

    const int gy0 = (i0 - 4) * 8;
    const int gx0 = (j0 - 4) * 8;
    const size_t arow0 = (size_t)(i * 8 + yh * 4) * WW;
    const int ja = (j0 + 2 * bg) * 8;

    for (int q = 0; q < NP; ++q) {
        const float* Tq = T + (size_t)q * HWPX;
        const float* Aq = A + (size_t)q * HWPX;
        __syncthreads();               // prev compute done before LDS overwrite
        // ---- stage target halo: async DMA, linear dest units, clamped src ----
        for (int w = tid; w < UNITS_TOT; w += NTHR) {
            const int dyr = w / UNITS_ROW;
            const int u   = w - dyr * UNITS_ROW;
            const int blk = u >> 4, v = u & 15;
            const int kb  = (blk >> 1) & 7;
            const int yh2 = v >> 3;
            const int m3  = (v & 7) ^ kb ^ (yh2 << 2);
            const int y   = (yh2 << 2) + (m3 >> 1);
            const int xh4 = m3 & 1;
            int gy = gy0 + dyr * 8 + y;
            int gx = gx0 + blk * 8 + xh4 * 4;
            gy = min(max(gy, 0), HH - 1);
            gx = min(max(gx, 0), WW - 4);
            async_copy16(Tq + (size_t)gy * WW + gx, Tt + dyr * DSTR + u * 4);
        }
        __syncthreads();               // auto vmcnt(0): DMA landed
        // ---- SAT: sliding 10-block window serves 2 anchors x 9 dx ----
        if (dyValid) {
            const float* tb = Tt + dr * DSTR + bg * 128 + yh * 32;
#pragma unroll
            for (int yi = 0; yi < 4; ++yi) {
                const float* arow_ = Aq + arow0 + (size_t)yi * WW + ja;
                const float4 aw0 = *(const float4*)(arow_);
                const float4 aw1 = *(const float4*)(arow_ + 4);
                const float4 aw2 = *(const float4*)(arow_ + 8);
                const float4 aw3 = *(const float4*)(arow_ + 12);
#pragma unroll
                for (int ph = 0; ph < 2; ++ph) {       // p-chunks of 5: 10-deep ds ILP
                    float4 tw0[5], tw1[5];
#pragma unroll
                    for (int pp = 0; pp < 5; ++pp) {
                        const int p  = ph * 5 + pp;
                        const int o0 = (yi * 8) ^ xq[p >> 1];
                        tw0[pp] = *(const float4*)(tb + p * 64 + o0);
                        tw1[pp] = *(const float4*)(tb + p * 64 + (o0 ^ 4));
                    }
#pragma unroll
                    for (int pp = 0; pp < 5; ++pp) {
                        const int p = ph * 5 + pp;
                        if (p < 9) CHAINAT(aw0, aw1, tw0[pp], tw1[pp], acc0[p]);
                        if (p > 0) CHAINAT(aw2, aw3, tw0[pp], tw1[pp], acc1[p - 1]);
                    }
                }
            }
        }
    }
    // ---- y-half merge via LDS (aliases Tt, barrier-protected) ----
    __syncthreads();
    double* yred = (double*)lds;                     // 108 pairs * 18 f64 = 3888 dw
    const int pairId = (it * NBG + bg) * 9 + dy;
    if (act && yh == 1) {
        double* d = yred + pairId * 18;
#pragma unroll
        for (int k = 0; k < 9; ++k) { d[k] = acc0[k]; d[9 + k] = acc1[k]; }
    }
    __syncthreads();
    double* redc = (double*)(lds + 8192);            // 216 f64 = 432 dw
    int*    redk = (int*)(lds + 8192 + 432);         // 216 int
    int*    bestpack = (int*)(lds + 9000);           // 24 int (FUSED path)
    if (act && yh == 0) {
        const double* d = yred + pairId * 18;
#pragma unroll
        for (int k = 0; k < 9; ++k) { acc0[k] += d[k]; acc1[k] += d[9 + k]; }
        // stage-1 argmin over dx: V = stsum(exact f64) - 2*SAT.
#pragma unroll
        for (int a2 = 0; a2 < 2; ++a2) {
            double bc = 1e300; int bk = -1;
            const int jb = j0 + 2 * bg + a2;
#pragma unroll
            for (int dxi = 0; dxi < 9; ++dxi) {
                const int gj = jb + dxi - 4;
                if (dyValid && gj >= 0 && gj < GW) {
                    const double sat = a2 ? acc1[dxi] : acc0[dxi];
                    const double c = stsumF[gi * GW + gj] - 2.0 * sat;
                    if (c < bc) { bc = c; bk = dy * 9 + dxi; }
                }
            }
            redc[(it * 9 + dy) * JT + 2 * bg + a2] = bc;
            redk[(it * 9 + dy) * JT + 2 * bg + a2] = bk;
        }
    }
    __syncthreads();
    // ---- stage-2 argmin over dy (ascending, strict <) ----
    if (tid < IT * JT) {
        const int it2 = tid / JT, jt = tid % JT;
        if (i0 + it2 < GH) {
            double c = 1e300; int k = -1;
#pragma unroll
            for (int dyi = 0; dyi < 9; ++dyi) {
                const double v = redc[(it2 * 9 + dyi) * JT + jt];
                if (v < c) { c = v; k = redk[(it2 * 9 + dyi) * JT + jt]; }
            }
            const int dyi = k / 9, dxi = k % 9;
            const int bi = i0 + it2 + dyi - 4;
            const int bj = j0 + jt + dxi - 4;
            if (FUSED) bestpack[tid] = (bi << 8) | bj;
            else       bestidx[(i0 + it2) * GW + j0 + jt] = (bi << 8) | bj;
        }
    }
    // ---- FUSED epilogue: write this WG's 24 output blocks x 12 planes.
    //      Overlaps round-2 compute of other WGs (1.8 dispatch rounds). ----
    if (FUSED) {
        __syncthreads();
        for (int w = tid; w < IT * JT * NP * 8 * 2; w += NTHR) {   // 4608 units
            const int gidx = w / 24;               // q*16 + it*8 + y
            const int u    = w - gidx * 24;        // jt*2 + xh
            const int q = gidx >> 4, it2 = (gidx >> 3) & 1, y = gidx & 7;
            if (i0 + it2 < GH) {
                const int jt = u >> 1, xh = (u & 1) * 4;
                const int idx = bestpack[it2 * JT + jt];
                const int bi = idx >> 8, bj = idx & 255;
                const float4 v = *(const float4*)(A + (size_t)q * HWPX
                                 + (size_t)(bi * 8 + y) * WW + bj * 8 + xh);
                *(float4*)(out + (size_t)q * HWPX
                           + (size_t)((i0 + it2) * 8 + y) * WW
                           + (size_t)(j0 + jt) * 8 + xh) = v;
            }
        }
    }
}

__global__ void __launch_bounds__(256) hbma_gather_kernel(const float* __restrict__ A,
                                                          const int* __restrict__ bestidx,
                                                          float* __restrict__ out) {
    const int tid = blockIdx.x * 256 + threadIdx.x;
    const int q   = tid / (HWPX / 4);
    const int rem = tid % (HWPX / 4);
    const int py  = rem / (WW / 4);
    const int c4  = rem % (WW / 4);
    const int i = py >> 3, y = py & 7;
    const int j = c4 >> 1, xh = (c4 & 1) * 4;
    const int idx = bestidx[i * GW + j];
    const int bi = idx >> 8, bj = idx & 255;
    const float4 v = *(const float4*)(A + (size_t)q * HWPX + (size_t)(bi * 8 + y) * WW + bj * 8 + xh);
    *(float4*)(out + (size_t)q * HWPX + (size_t)py * WW + c4 * 4) = v;
}

extern "C" void kernel_launch(void* const* d_in, const int* in_sizes, int n_in,
                              void* d_out, int out_size, void* d_ws, size_t ws_size,
                              hipStream_t stream) {
    const float* A = (const float*)d_in[0];
    const float* T = (const float*)d_in[1];
    float* out = (float*)d_out;

    const bool fused = ws_size >= (size_t)NBLK * 8 + 1024;   // stsum fits d_ws?

    if (fused) {
        double* st2f = (double*)d_ws;
        hipFuncSetAttribute((const void*)hbma_cost_kernel<true>,
                            hipFuncAttributeMaxDynamicSharedMemorySize, TT_DW * 4);
        hipLaunchKernelGGL(hbma_st2_kernel, dim3(NBLK / 16), dim3(256),
                           0, stream, T, st2f);
        hipLaunchKernelGGL(HIP_KERNEL_NAME(hbma_cost_kernel<true>),
                           dim3(NWG), dim3(NTHR), TT_DW * 4, stream,
                           A, T, st2f, (int*)nullptr, out);
    } else {
        // r22 fallback: stsum scratch in d_out (gather overwrites), bestidx in d_ws
        int* bestidx = (int*)d_ws;
        double* st2f = (double*)d_out + ST2_FINAL_OFF;
        hipFuncSetAttribute((const void*)hbma_cost_kernel<false>,
                            hipFuncAttributeMaxDynamicSharedMemorySize, TT_DW * 4);
        hipLaunchKernelGGL(hbma_st2_kernel, dim3(NBLK / 16), dim3(256),
                           0, stream, T, st2f);
        hipLaunchKernelGGL(HIP_KERNEL_NAME(hbma_cost_kernel<false>),
                           dim3(NWG), dim3(NTHR), TT_DW * 4, stream,
                           A, T, st2f, bestidx, (float*)nullptr);
        const int total4 = (NP * HWPX) / 4;
        hipLaunchKernelGGL(hbma_gather_kernel, dim3(total4 / 256), dim3(256),
                           0, stream, A, bestidx, out);
    }
}

// Round 24
// 186.588 us; speedup vs baseline: 1.2260x; 1.0458x over previous
//
#include <hip/hip_runtime.h>

#define GH 135
#define GW 240
#define HH 1080
#define WW 1920
#define HWPX (HH*WW)
#define NP 12
#define IT 3               // anchor block-rows per WG (135 = 45*3 exact)
#define JT 8               // anchor blocks (j) per WG
#define NBG 4              // anchor pairs per it-row
#define NIG 45             // GH/IT exact
#define NJG 30             // GW/JT exact
#define TROWS (IT+8)       // 11 staged target block-rows
#define TBLK (JT+8)        // 16 staged target blocks per dy-row (= exactly 4 waves!)
#define DSTR (TBLK*64+8)   // 1032 dw: %32==8 -> 2-quad row rotation (r12)
#define UNITS_ROW (TBLK*16)// 256 16B-units per dy-row = 4 whole waves (DMA rule)
#define UNITS_TOT (TROWS*UNITS_ROW) // 2816 = exactly 11 x 256-thread iterations
#define NTHR 256
#define NACT 216           // 9 dy * (3 it * 4 bg * 2 yh) = 84% active
#define TT_DW (TROWS*DSTR) // 11352 dw = 45408 B -> 3 WG/CU at VGPR<=85
#define NWG (NIG*NJG)      // 1350 (not /8 -> m204 bijective swizzle)
#define NBLK (GH*GW)       // 32400 target blocks
#define ST2_FINAL_OFF 262144   // d_out fallback scratch (double-index)

// Round-24 = r23 fused champion with IT=3/JT=8 geometry: staged halo blocks
// per anchor 8.33 -> 7.33 (-13% staging DMA + FETCH — instruction-count cuts
// are the only lever type that has ever won: r11/r19/r20/r23). Bonus: 16-block
// halo row = 256 units = 4 WHOLE waves -> global_load_lds wave-uniform rule
// holds with zero pad waste. All feasibility invariants preserved: NACT=216,
// LDS 45.4KB -> 3 WG/CU, A=2 windows, VGPR<=85 inner loop, no ragged i-strip.
// NWG=1350 (%8=6) -> m204 BIJECTIVE XCD swizzle (simple form would be wrong).
// Algebra (r19/r20): argmin(stsum_f64 - 2*A.T), ||A||^2 dropped. Swizzle
// (bijective, r5/r12): stored(blk,y,xh)=blk*64+((y*8+xh)^4*kb^16*(y>>2)),
// kb=(blk>>1)&7 (window base 2bg even -> xq formula unchanged).

// 8-px fp32 DOT chain + f64 accumulate (argmin-exact, proven r19-r23)
#define CHAINAT(AV0, AV1, T0, T1, ACC) do { \
    float _s = (AV0).x * (T0).x; \
    _s = fmaf((AV0).y, (T0).y, _s); \
    _s = fmaf((AV0).z, (T0).z, _s); \
    _s = fmaf((AV0).w, (T0).w, _s); \
    _s = fmaf((AV1).x, (T1).x, _s); \
    _s = fmaf((AV1).y, (T1).y, _s); \
    _s = fmaf((AV1).z, (T1).z, _s); \
    _s = fmaf((AV1).w, (T1).w, _s); \
    (ACC) += (double)_s; } while(0)

__device__ __forceinline__ void async_copy16(const float* gp, float* lp) {
#if __has_builtin(__builtin_amdgcn_global_load_lds)
    __builtin_amdgcn_global_load_lds(
        (const __attribute__((address_space(1))) void*)gp,
        (__attribute__((address_space(3))) void*)lp, 16, 0, 0);
#else
    *(float4*)lp = *(const float4*)gp;
#endif
}

// ---- ||T||^2 per target block: 16 blocks x 16 (y,qh) slices per WG (r21) ----
__global__ void __launch_bounds__(256) hbma_st2_kernel(const float* __restrict__ T,
                                                       double* __restrict__ stsum) {
    __shared__ double red[256];
    const int tid = threadIdx.x;
    const int b16 = tid & 15;
    const int s   = tid >> 4;
    const int bb  = blockIdx.x * 16 + b16;
    const int gi = bb / GW, gj = bb % GW;
    const int y  = s & 7, qh = s >> 3;
    const float* base = T + (size_t)(gi * 8 + y) * WW + gj * 8 + (size_t)(qh * 6) * HWPX;
    double acc = 0.0;
#pragma unroll
    for (int q = 0; q < 6; ++q) {
        const float* r = base + (size_t)q * HWPX;
        const float4 v0 = *(const float4*)(r);
        const float4 v1 = *(const float4*)(r + 4);
        acc += (double)v0.x * v0.x + (double)v0.y * v0.y
             + (double)v0.z * v0.z + (double)v0.w * v0.w
             + (double)v1.x * v1.x + (double)v1.y * v1.y
             + (double)v1.z * v1.z + (double)v1.w * v1.w;
    }
    red[s * 16 + b16] = acc;
    __syncthreads();
    if (tid < 16) {
        double t = 0.0;
#pragma unroll
        for (int k = 0; k < 16; ++k) t += red[k * 16 + tid];
        stsum[blockIdx.x * 16 + tid] = t;
    }
}

template<bool FUSED>
__global__ void __launch_bounds__(NTHR, 3)
hbma_cost_kernel(const float* __restrict__ A, const float* __restrict__ T,
                 const double* __restrict__ stsumF, int* __restrict__ bestidx,
                 float* __restrict__ out) {
    extern __shared__ float lds[];
    float* Tt = lds;

    // m204 BIJECTIVE XCD swizzle: 1350 WGs, q=168, r=6
    const int lin = blockIdx.x;
    const int xcd = lin & 7, pos = lin >> 3;
    const int qq = NWG / 8, rr = NWG % 8;     // 168, 6
    const int g = (xcd < rr) ? xcd * (qq + 1) + pos
                             : rr * (qq + 1) + (xcd - rr) * qq + pos;
    const int ig  = g % NIG, jg = g / NIG;
    const int i0  = ig * IT;
    const int j0  = jg * JT;

    const int tid = threadIdx.x;
    const int dy  = tid / 24;          // 0..8
    const int rem = tid % 24;
    const int it  = rem / 8;           // 0..2
    const int r2  = rem % 8;
    const int bg  = r2 >> 1;           // 0..3 (anchor pair)
    const int yh  = r2 & 1;            // y-half
    const bool act = (tid < NACT);
    const int i   = i0 + it;
    const int gi  = i + dy - 4;
    const bool dyValid = act && (gi >= 0) && (gi < GH);
    const int dr  = it + dy;           // staged row index 0..10

    int xq[5];                         // per p-pair h: 4*((bg+h)&7) ^ 16*yh
#pragma unroll
    for (int h = 0; h < 5; ++h) xq[h] = (((bg + h) & 7) * 4) ^ (yh << 4);

    double acc0[9], acc1[9];           // SAT accumulators
#pragma unroll
    for (int d = 0; d < 9; ++d) { acc0[d] = 0.0; acc1[d] = 0.0; }

    const int gy0 = (i0 - 4) * 8;
    const int gx0 = (j0 - 4) * 8;
    const size_t arow0 = (size_t)(i * 8 + yh * 4) * WW;
    const int ja = (j0 + 2 * bg) * 8;

    for (int q = 0; q < NP; ++q) {
        const float* Tq = T + (size_t)q * HWPX;
        const float* Aq = A + (size_t)q * HWPX;
        __syncthreads();               // prev compute done before LDS overwrite
        // ---- stage target halo: async DMA; 11 full rows, each = 256 units
        //      = 4 whole waves (wave-uniform-base rule, zero pad waste) ----
        for (int w = tid; w < UNITS_TOT; w += NTHR) {
            const int dyr = w >> 8;                 // w / UNITS_ROW
            const int u   = w & 255;
            const int blk = u >> 4, v = u & 15;
            const int kb  = (blk >> 1) & 7;
            const int yh2 = v >> 3;
            const int m3  = (v & 7) ^ kb ^ (yh2 << 2);
            const int y   = (yh2 << 2) + (m3 >> 1);
            const int xh4 = m3 & 1;
            int gy = gy0 + dyr * 8 + y;
            int gx = gx0 + blk * 8 + xh4 * 4;
            gy = min(max(gy, 0), HH - 1);           // clamp: garbage slots are
            gx = min(max(gx, 0), WW - 4);           // argmin-masked (r11)
            async_copy16(Tq + (size_t)gy * WW + gx, Tt + dyr * DSTR + u * 4);
        }
        __syncthreads();               // auto vmcnt(0): DMA landed
        // ---- SAT: sliding 10-block window serves 2 anchors x 9 dx ----
        if (dyValid) {
            const float* tb = Tt + dr * DSTR + bg * 128 + yh * 32;
#pragma unroll
            for (int yi = 0; yi < 4; ++yi) {
                const float* arow_ = Aq + arow0 + (size_t)yi * WW + ja;
                const float4 aw0 = *(const float4*)(arow_);
                const float4 aw1 = *(const float4*)(arow_ + 4);
                const float4 aw2 = *(const float4*)(arow_ + 8);
                const float4 aw3 = *(const float4*)(arow_ + 12);
#pragma unroll
                for (int ph = 0; ph < 2; ++ph) {       // p-chunks of 5: 10-deep ds ILP
                    float4 tw0[5], tw1[5];
#pragma unroll
                    for (int pp = 0; pp < 5; ++pp) {
                        const int p  = ph * 5 + pp;
                        const int o0 = (yi * 8) ^ xq[p >> 1];
                        tw0[pp] = *(const float4*)(tb + p * 64 + o0);
                        tw1[pp] = *(const float4*)(tb + p * 64 + (o0 ^ 4));
                    }
#pragma unroll
                    for (int pp = 0; pp < 5; ++pp) {
                        const int p = ph * 5 + pp;
                        if (p < 9) CHAINAT(aw0, aw1, tw0[pp], tw1[pp], acc0[p]);
                        if (p > 0) CHAINAT(aw2, aw3, tw0[pp], tw1[pp], acc1[p - 1]);
                    }
                }
            }
        }
    }
    // ---- y-half merge via LDS (aliases Tt, barrier-protected) ----
    __syncthreads();
    double* yred = (double*)lds;                     // 108 pairs * 18 f64 = 3888 dw
    const int pairId = (it * NBG + bg) * 9 + dy;     // 0..107
    if (act && yh == 1) {
        double* d = yred + pairId * 18;
#pragma unroll
        for (int k = 0; k < 9; ++k) { d[k] = acc0[k]; d[9 + k] = acc1[k]; }
    }
    __syncthreads();
    double* redc = (double*)(lds + 8192);            // 216 f64 = 432 dw
    int*    redk = (int*)(lds + 8192 + 432);         // 216 int
    int*    bestpack = (int*)(lds + 9000);           // 24 int (FUSED path)
    if (act && yh == 0) {
        const double* d = yred + pairId * 18;
#pragma unroll
        for (int k = 0; k < 9; ++k) { acc0[k] += d[k]; acc1[k] += d[9 + k]; }
        // stage-1 argmin over dx: V = stsum(exact f64) - 2*SAT.
        // Ascending dx, strict < -> first-k ties (matches np argmin).
#pragma unroll
        for (int a2 = 0; a2 < 2; ++a2) {
            double bc = 1e300; int bk = -1;
            const int jb = j0 + 2 * bg + a2;
#pragma unroll
            for (int dxi = 0; dxi < 9; ++dxi) {
                const int gj = jb + dxi - 4;
                if (dyValid && gj >= 0 && gj < GW) {
                    const double sat = a2 ? acc1[dxi] : acc0[dxi];
                    const double c = stsumF[gi * GW + gj] - 2.0 * sat;
                    if (c < bc) { bc = c; bk = dy * 9 + dxi; }
                }
            }
            redc[(it * 9 + dy) * JT + 2 * bg + a2] = bc;
            redk[(it * 9 + dy) * JT + 2 * bg + a2] = bk;
        }
    }
    __syncthreads();
    // ---- stage-2 argmin over dy (ascending, strict <) ----
    if (tid < IT * JT) {               // 24 threads
        const int it2 = tid / JT, jt = tid % JT;
        double c = 1e300; int k = -1;
#pragma unroll
        for (int dyi = 0; dyi < 9; ++dyi) {
            const double v = redc[(it2 * 9 + dyi) * JT + jt];
            if (v < c) { c = v; k = redk[(it2 * 9 + dyi) * JT + jt]; }
        }
        const int dyi = k / 9, dxi = k % 9;
        const int bi = i0 + it2 + dyi - 4;
        const int bj = j0 + jt + dxi - 4;
        if (FUSED) bestpack[tid] = (bi << 8) | bj;
        else       bestidx[(i0 + it2) * GW + j0 + jt] = (bi << 8) | bj;
    }
    // ---- FUSED epilogue: write this WG's 24 output blocks x 12 planes.
    //      Overlaps round-2 compute of other WGs (~1.76 dispatch rounds). ----
    if (FUSED) {
        __syncthreads();
        for (int w = tid; w < IT * JT * NP * 8 * 2; w += NTHR) {   // 4608 units
            const int gidx = w >> 4;               // q*24 + it2*8 + y
            const int u    = w & 15;               // jt*2 + xh
            const int q = gidx / 24, rr2 = gidx % 24;
            const int it2 = rr2 >> 3, y = rr2 & 7;
            const int jt = u >> 1, xh = (u & 1) * 4;
            const int idx = bestpack[it2 * JT + jt];
            const int bi = idx >> 8, bj = idx & 255;
            const float4 v = *(const float4*)(A + (size_t)q * HWPX
                             + (size_t)(bi * 8 + y) * WW + bj * 8 + xh);
            *(float4*)(out + (size_t)q * HWPX
                       + (size_t)((i0 + it2) * 8 + y) * WW
                       + (size_t)(j0 + jt) * 8 + xh) = v;
        }
    }
}

__global__ void __launch_bounds__(256) hbma_gather_kernel(const float* __restrict__ A,
                                                          const int* __restrict__ bestidx,
                                                          float* __restrict__ out) {
    const int tid = blockIdx.x * 256 + threadIdx.x;
    const int q   = tid / (HWPX / 4);
    const int rem = tid % (HWPX / 4);
    const int py  = rem / (WW / 4);
    const int c4  = rem % (WW / 4);
    const int i = py >> 3, y = py & 7;
    const int j = c4 >> 1, xh = (c4 & 1) * 4;
    const int idx = bestidx[i * GW + j];
    const int bi = idx >> 8, bj = idx & 255;
    const float4 v = *(const float4*)(A + (size_t)q * HWPX + (size_t)(bi * 8 + y) * WW + bj * 8 + xh);
    *(float4*)(out + (size_t)q * HWPX + (size_t)py * WW + c4 * 4) = v;
}

extern "C" void kernel_launch(void* const* d_in, const int* in_sizes, int n_in,
                              void* d_out, int out_size, void* d_ws, size_t ws_size,
                              hipStream_t stream) {
    const float* A = (const float*)d_in[0];
    const float* T = (const float*)d_in[1];
    float* out = (float*)d_out;

    const bool fused = ws_size >= (size_t)NBLK * 8 + 1024;   // stsum fits d_ws?

    if (fused) {
        double* st2f = (double*)d_ws;
        hipFuncSetAttribute((const void*)hbma_cost_kernel<true>,
                            hipFuncAttributeMaxDynamicSharedMemorySize, TT_DW * 4);
        hipLaunchKernelGGL(hbma_st2_kernel, dim3(NBLK / 16), dim3(256),
                           0, stream, T, st2f);
        hipLaunchKernelGGL(HIP_KERNEL_NAME(hbma_cost_kernel<true>),
                           dim3(NWG), dim3(NTHR), TT_DW * 4, stream,
                           A, T, st2f, (int*)nullptr, out);
    } else {
        // fallback: stsum scratch in d_out (gather overwrites), bestidx in d_ws
        int* bestidx = (int*)d_ws;
        double* st2f = (double*)d_out + ST2_FINAL_OFF;
        hipFuncSetAttribute((const void*)hbma_cost_kernel<false>,
                            hipFuncAttributeMaxDynamicSharedMemorySize, TT_DW * 4);
        hipLaunchKernelGGL(hbma_st2_kernel, dim3(NBLK / 16), dim3(256),
                           0, stream, T, st2f);
        hipLaunchKernelGGL(HIP_KERNEL_NAME(hbma_cost_kernel<false>),
                           dim3(NWG), dim3(NTHR), TT_DW * 4, stream,
                           A, T, st2f, bestidx, (float*)nullptr);
        const int total4 = (NP * HWPX) / 4;
        hipLaunchKernelGGL(hbma_gather_kernel, dim3(total4 / 256), dim3(256),
                           0, stream, A, bestidx, out);
    }
}